// Round 5
// baseline (937.887 us; speedup 1.0000x reference)
//
#include <hip/hip_runtime.h>
#include <stdint.h>

#define NN 50000
#define NPAD 50048   // padded row count so 128-row GEMM tiles never read OOB
#define NE 800000
#define DIM 256
#define DPB 782      // dsts per agg block (64 blocks/slice * 782 >= NN)

typedef __attribute__((ext_vector_type(8))) short short8;
typedef __attribute__((ext_vector_type(4))) unsigned short ushort4v;
typedef __attribute__((ext_vector_type(8))) unsigned short ushort8v;
typedef __attribute__((ext_vector_type(4))) float floatx4;

__device__ __forceinline__ uint16_t f2bf(float f) {
  union { float f; uint32_t u; } v; v.f = f;
  uint32_t r = v.u + 0x7fffu + ((v.u >> 16) & 1u);
  return (uint16_t)(r >> 16);
}
__device__ __forceinline__ float bf2f(uint16_t h) {
  union { uint32_t u; float f; } v; v.u = ((uint32_t)h) << 16;
  return v.f;
}

// async global->LDS, 16B per lane; dest = wave-uniform base + lane*16
__device__ __forceinline__ void stage16(const uint16_t* gp, short* lbase, int lane) {
#if __has_builtin(__builtin_amdgcn_global_load_lds)
  __builtin_amdgcn_global_load_lds((__attribute__((address_space(1))) void*)gp,
                                   (__attribute__((address_space(3))) void*)lbase,
                                   16, 0, 0);
#else
  *(ushort8v*)((uint16_t*)lbase + lane * 8) = *(const ushort8v*)gp;
#endif
}

// ---------------- CSR build ----------------
__global__ __launch_bounds__(256) void k_zero(int* __restrict__ p, int n) {
  int i = blockIdx.x * 256 + threadIdx.x;
  if (i < n) p[i] = 0;
}

__global__ __launch_bounds__(256) void k_hist(const int* __restrict__ dst,
                                              int* __restrict__ hist) {
  int e = blockIdx.x * 256 + threadIdx.x;
  if (e < NE) atomicAdd(&hist[dst[e]], 1);
}

__global__ __launch_bounds__(256) void k_scan1(const int* __restrict__ hist,
                                               int* __restrict__ rowptr,
                                               int* __restrict__ bsums) {
  __shared__ int s[256];
  int i = blockIdx.x * 256 + threadIdx.x;
  int v = (i < NN) ? hist[i] : 0;
  s[threadIdx.x] = v;
  __syncthreads();
  for (int off = 1; off < 256; off <<= 1) {
    int t = (threadIdx.x >= off) ? s[threadIdx.x - off] : 0;
    __syncthreads();
    s[threadIdx.x] += t;
    __syncthreads();
  }
  if (i < NN) rowptr[i] = s[threadIdx.x] - v;  // exclusive (local)
  if (threadIdx.x == 255) bsums[blockIdx.x] = s[255];
}

__global__ __launch_bounds__(256) void k_scan2(int* __restrict__ bsums,
                                               int* __restrict__ rowptr, int nb) {
  __shared__ int s[256];
  int v = (threadIdx.x < nb) ? bsums[threadIdx.x] : 0;
  s[threadIdx.x] = v;
  __syncthreads();
  for (int off = 1; off < 256; off <<= 1) {
    int t = (threadIdx.x >= off) ? s[threadIdx.x - off] : 0;
    __syncthreads();
    s[threadIdx.x] += t;
    __syncthreads();
  }
  if (threadIdx.x < nb) bsums[threadIdx.x] = s[threadIdx.x] - v;  // exclusive
  if (threadIdx.x == 0) rowptr[NN] = NE;
}

__global__ __launch_bounds__(256) void k_scan3(const int* __restrict__ hist,
                                               int* __restrict__ rowptr,
                                               const int* __restrict__ bsums,
                                               float* __restrict__ dinv) {
  int i = blockIdx.x * 256 + threadIdx.x;
  if (i < NN) {
    rowptr[i] += bsums[blockIdx.x];
    dinv[i] = rsqrtf((float)(hist[i] + 1));  // +1 self-loop; deg >= 1 always
  }
}

__global__ __launch_bounds__(256) void k_fill(const int* __restrict__ src,
                                              const int* __restrict__ dst,
                                              const int* __restrict__ rowptr,
                                              int* __restrict__ fill,
                                              int* __restrict__ csr) {
  int e = blockIdx.x * 256 + threadIdx.x;
  if (e < NE) {
    int d = dst[e];
    int p = rowptr[d] + atomicAdd(&fill[d], 1);
    csr[p] = src[e];
  }
}

// ---------------- prep: W (fp32 [k][n]) -> Wt (bf16 [n][k]) ----------------
__global__ __launch_bounds__(256) void k_prep_w(const float* __restrict__ W,
                                                uint16_t* __restrict__ Wt) {
  __shared__ float t[32][33];
  int bx = blockIdx.x & 7, by = blockIdx.x >> 3;
  int tx = threadIdx.x & 31, ty = threadIdx.x >> 5;  // 32 x 8
#pragma unroll
  for (int p = 0; p < 4; ++p)
    t[ty + p * 8][tx] = W[(size_t)(by * 32 + ty + p * 8) * 256 + bx * 32 + tx];
  __syncthreads();
#pragma unroll
  for (int p = 0; p < 4; ++p)
    Wt[(size_t)(bx * 32 + ty + p * 8) * 256 + by * 32 + tx] = f2bf(t[tx][ty + p * 8]);
}

// ---------------- prep: x fp32 -> hi/lo bf16 (exact split) ----------------
__global__ __launch_bounds__(256) void k_split(const float* __restrict__ x,
                                               uint16_t* __restrict__ hi,
                                               uint16_t* __restrict__ lo) {
  size_t i = (size_t)(blockIdx.x * 256 + threadIdx.x) * 4;  // 12.8M floats total
  float4 v = *(const float4*)(x + i);
  float a[4] = {v.x, v.y, v.z, v.w};
  ushort4v h, l;
#pragma unroll
  for (int u = 0; u < 4; ++u) {
    uint16_t hh = f2bf(a[u]);
    h[u] = hh;
    l[u] = f2bf(a[u] - bf2f(hh));
  }
  *(ushort4v*)(hi + i) = h;
  *(ushort4v*)(lo + i) = l;
}

// ---------------- GEMM (m97-style): g2[slice][row][32] = dinv[row] * (Ah[+Al]) @ Wt^T ----
// Ah/Al: bf16 [NPAD][256] row-major; Wt: bf16 [256 n][256 k];
// output: slice-major bf16, slice s = col>>5, 3.2MB per slice region (per-XCD L2-resident).
#define BM 128
#define BN 128
#define BK 32

template <int SPLIT>
__global__ __launch_bounds__(256) void k_gemm(const uint16_t* __restrict__ Ah,
                                              const uint16_t* __restrict__ Al,
                                              const uint16_t* __restrict__ Wt,
                                              const float* __restrict__ dinv,
                                              uint16_t* __restrict__ g2, int M) {
  __shared__ short Ash[BM * BK];
  __shared__ short Asl[BM * BK];
  __shared__ short Bs[BN * BK];

  const int tid = threadIdx.x;
  const int wave = tid >> 6, lane = tid & 63;
  const int wm = wave >> 1, wn = wave & 1;
  const int m16 = lane & 15, q = lane >> 4;
  const int rowBase = blockIdx.x * BM;
  const int colBase = blockIdx.y * BN;
  const int rsub = lane >> 2;          // 0..15
  const int kch = (lane & 3) * 8;      // bf16-elem offset within BK chunk

  floatx4 acc[4][4];
#pragma unroll
  for (int i = 0; i < 4; ++i)
#pragma unroll
    for (int j = 0; j < 4; ++j) acc[i][j] = (floatx4)(0.0f);

  for (int k0 = 0; k0 < DIM; k0 += BK) {
    __syncthreads();
#pragma unroll
    for (int p = 0; p < 2; ++p) {
      int rb = wave * 16 + p * 64;
      stage16(Ah + (size_t)(rowBase + rb + rsub) * DIM + k0 + kch, &Ash[rb * BK], lane);
      if (SPLIT)
        stage16(Al + (size_t)(rowBase + rb + rsub) * DIM + k0 + kch, &Asl[rb * BK], lane);
      stage16(Wt + (size_t)(colBase + rb + rsub) * DIM + k0 + kch, &Bs[rb * BK], lane);
    }
    __syncthreads();

    short8 ah[4], al[4], b[4];
#pragma unroll
    for (int i = 0; i < 4; ++i) {
      int r = wm * 64 + i * 16 + m16;
      ah[i] = *(const short8*)(&Ash[r * BK + q * 8]);
      if (SPLIT) al[i] = *(const short8*)(&Asl[r * BK + q * 8]);
    }
#pragma unroll
    for (int j = 0; j < 4; ++j) {
      int n = wn * 64 + j * 16 + m16;
      b[j] = *(const short8*)(&Bs[n * BK + q * 8]);
    }
#pragma unroll
    for (int i = 0; i < 4; ++i)
#pragma unroll
      for (int j = 0; j < 4; ++j) {
        if (SPLIT)
          acc[i][j] = __builtin_amdgcn_mfma_f32_16x16x32_bf16(al[i], b[j], acc[i][j], 0, 0, 0);
        acc[i][j] = __builtin_amdgcn_mfma_f32_16x16x32_bf16(ah[i], b[j], acc[i][j], 0, 0, 0);
      }
  }

  // epilogue: C/D layout col = lane&15, row = q*4 + reg; prescale by dinv[row],
  // write slice-major.
#pragma unroll
  for (int i = 0; i < 4; ++i) {
#pragma unroll
    for (int reg = 0; reg < 4; ++reg) {
      int row = rowBase + wm * 64 + i * 16 + q * 4 + reg;
      if (row < M) {
        float dd = dinv[row];
#pragma unroll
        for (int j = 0; j < 4; ++j) {
          int col = colBase + wn * 64 + j * 16 + m16;
          int sl = col >> 5, cc = col & 31;
          g2[(size_t)sl * NN * 32 + (size_t)row * 32 + cc] = f2bf(acc[i][j][reg] * dd);
        }
      }
    }
  }
}

// ---------------- Aggregation: XCD-sliced pull ----------------
// slice = blockIdx&7 -> (with round-robin dispatch) all blocks of slice s run on
// XCD s and touch only that slice's 3.2MB region -> L2-resident gather.
// g2 rows are prescaled by dinv[src]; out[d] = post(dinv[d]*(sum + self) + b).
template <int FINAL>
__global__ __launch_bounds__(256) void k_agg(const uint16_t* __restrict__ g2,
                                             const int* __restrict__ rowptr,
                                             const int* __restrict__ csr,
                                             const float* __restrict__ dinv,
                                             const float* __restrict__ bias,
                                             const float* __restrict__ x,
                                             uint16_t* __restrict__ outb,
                                             float* __restrict__ outf) {
  const int slice = blockIdx.x & 7;
  const int nb = blockIdx.x >> 3;               // 0..63
  const int wave = threadIdx.x >> 6, lane = threadIdx.x & 63;
  const int group = lane >> 3, li = lane & 7;   // 8 edge-groups x 8 lanes
  const uint16_t* gs = g2 + (size_t)slice * NN * 32;
  const int fbase = slice * 32 + li * 4;

  int dend = nb * DPB + DPB;
  if (dend > NN) dend = NN;

  for (int d = nb * DPB + wave; d < dend; d += 4) {
    int e0 = rowptr[d], e1 = rowptr[d + 1];
    float a0 = 0.f, a1 = 0.f, a2 = 0.f, a3 = 0.f;
    for (int e = e0 + group; e < e1; e += 8) {
      int s = csr[e];
      ushort4v v = *(const ushort4v*)(gs + (size_t)s * 32 + li * 4);
      a0 += bf2f(v[0]); a1 += bf2f(v[1]); a2 += bf2f(v[2]); a3 += bf2f(v[3]);
    }
    // combine 8 groups -> group 0
#pragma unroll
    for (int off = 8; off <= 32; off <<= 1) {
      a0 += __shfl_down(a0, off);
      a1 += __shfl_down(a1, off);
      a2 += __shfl_down(a2, off);
      a3 += __shfl_down(a3, off);
    }
    if (group == 0) {
      ushort4v sv = *(const ushort4v*)(gs + (size_t)d * 32 + li * 4);
      a0 += bf2f(sv[0]); a1 += bf2f(sv[1]); a2 += bf2f(sv[2]); a3 += bf2f(sv[3]);
      float dd = dinv[d];
      float4 bv = *(const float4*)(bias + fbase);
      float r0 = fmaxf(dd * a0 + bv.x, 0.f);
      float r1 = fmaxf(dd * a1 + bv.y, 0.f);
      float r2 = fmaxf(dd * a2 + bv.z, 0.f);
      float r3 = fmaxf(dd * a3 + bv.w, 0.f);
      if (FINAL) {
        float4 xv = *(const float4*)(x + (size_t)d * DIM + fbase);
        float4 o;
        o.x = (xv.x + r0) * 0.5f;
        o.y = (xv.y + r1) * 0.5f;
        o.z = (xv.z + r2) * 0.5f;
        o.w = (xv.w + r3) * 0.5f;
        *(float4*)(outf + (size_t)d * DIM + fbase) = o;
      } else {
        ushort4v o;
        o[0] = f2bf(r0); o[1] = f2bf(r1); o[2] = f2bf(r2); o[3] = f2bf(r3);
        *(ushort4v*)(outb + (size_t)d * DIM + fbase) = o;
      }
    }
  }
}

// ---------------- launch ----------------
extern "C" void kernel_launch(void* const* d_in, const int* in_sizes, int n_in,
                              void* d_out, int out_size, void* d_ws, size_t ws_size,
                              hipStream_t stream) {
  const float* x  = (const float*)d_in[0];
  const int*   ei = (const int*)d_in[1];   // [2 x NE]: src row, then dst row
  const float* W1 = (const float*)d_in[2];
  const float* b1 = (const float*)d_in[3];
  const float* W2 = (const float*)d_in[4];
  const float* b2 = (const float*)d_in[5];
  float* out = (float*)d_out;

  // workspace layout (all bf16 arrays 16B-aligned)
  int*      hist   = (int*)d_ws;               // NN
  int*      fill   = hist + NN;                // NN
  int*      rowptr = fill + NN;                // NN+1 (padded to 50008)
  int*      bsums  = rowptr + 50008;           // 256
  int*      csr    = bsums + 256;              // NE
  float*    dinv   = (float*)(csr + NE);       // NN
  uint16_t* Wt1    = (uint16_t*)(dinv + NN);   // 256*256
  uint16_t* Wt2    = Wt1 + 256 * 256;          // 256*256
  uint16_t* x_hi   = Wt2 + 256 * 256;          // NPAD*DIM
  uint16_t* x_lo   = x_hi + (size_t)NPAD * DIM;
  uint16_t* g2     = x_lo + (size_t)NPAD * DIM;  // NN*DIM (slice-major, 8x3.2MB)
  uint16_t* h1     = g2 + (size_t)NN * DIM;      // NPAD*DIM row-major

  const int* esrc = ei;
  const int* edst = ei + NE;

  k_zero<<<(2 * NN + 255) / 256, 256, 0, stream>>>(hist, 2 * NN);
  k_hist<<<(NE + 255) / 256, 256, 0, stream>>>(edst, hist);
  k_scan1<<<196, 256, 0, stream>>>(hist, rowptr, bsums);
  k_scan2<<<1, 256, 0, stream>>>(bsums, rowptr, 196);
  k_scan3<<<196, 256, 0, stream>>>(hist, rowptr, bsums, dinv);
  k_fill<<<(NE + 255) / 256, 256, 0, stream>>>(esrc, edst, rowptr, fill, csr);

  k_prep_w<<<64, 256, 0, stream>>>(W1, Wt1);
  k_prep_w<<<64, 256, 0, stream>>>(W2, Wt2);
  k_split<<<12500, 256, 0, stream>>>(x, x_hi, x_lo);  // 12.8M floats / 4 / 256

  dim3 ggrid((NN + BM - 1) / BM, DIM / BN);
  k_gemm<1><<<ggrid, 256, 0, stream>>>(x_hi, x_lo, Wt1, dinv, g2, NN);
  k_agg<0><<<512, 256, 0, stream>>>(g2, rowptr, csr, dinv, b1, nullptr, h1, nullptr);
  k_gemm<0><<<ggrid, 256, 0, stream>>>(h1, nullptr, Wt2, dinv, g2, NN);
  k_agg<1><<<512, 256, 0, stream>>>(g2, rowptr, csr, dinv, b2, x, nullptr, out);
}

// Round 6
// 506.969 us; speedup vs baseline: 1.8500x; 1.8500x over previous
//
#include <hip/hip_runtime.h>
#include <stdint.h>

#define NN 50000
#define NPAD 50048   // padded row count so 128-row GEMM tiles never read OOB
#define NE 800000
#define DIM 256

typedef __attribute__((ext_vector_type(8))) short short8;
typedef __attribute__((ext_vector_type(2))) unsigned short ushort2v;
typedef __attribute__((ext_vector_type(4))) unsigned short ushort4v;
typedef __attribute__((ext_vector_type(8))) unsigned short ushort8v;
typedef __attribute__((ext_vector_type(4))) float floatx4;

__device__ __forceinline__ uint16_t f2bf(float f) {
  union { float f; uint32_t u; } v; v.f = f;
  uint32_t r = v.u + 0x7fffu + ((v.u >> 16) & 1u);
  return (uint16_t)(r >> 16);
}
__device__ __forceinline__ float bf2f(uint16_t h) {
  union { uint32_t u; float f; } v; v.u = ((uint32_t)h) << 16;
  return v.f;
}

// async global->LDS, 16B per lane; dest = wave-uniform base + lane*16
__device__ __forceinline__ void stage16(const uint16_t* gp, short* lbase, int lane) {
#if __has_builtin(__builtin_amdgcn_global_load_lds)
  __builtin_amdgcn_global_load_lds((__attribute__((address_space(1))) void*)gp,
                                   (__attribute__((address_space(3))) void*)lbase,
                                   16, 0, 0);
#else
  *(ushort8v*)((uint16_t*)lbase + lane * 8) = *(const ushort8v*)gp;
#endif
}

// ---------------- CSR build ----------------
__global__ __launch_bounds__(256) void k_zero(int* __restrict__ p, int n) {
  int i = blockIdx.x * 256 + threadIdx.x;
  if (i < n) p[i] = 0;
}

__global__ __launch_bounds__(256) void k_hist(const int* __restrict__ dst,
                                              int* __restrict__ hist) {
  int e = blockIdx.x * 256 + threadIdx.x;
  if (e < NE) atomicAdd(&hist[dst[e]], 1);
}

__global__ __launch_bounds__(256) void k_scan1(const int* __restrict__ hist,
                                               int* __restrict__ rowptr,
                                               int* __restrict__ bsums) {
  __shared__ int s[256];
  int i = blockIdx.x * 256 + threadIdx.x;
  int v = (i < NN) ? hist[i] : 0;
  s[threadIdx.x] = v;
  __syncthreads();
  for (int off = 1; off < 256; off <<= 1) {
    int t = (threadIdx.x >= off) ? s[threadIdx.x - off] : 0;
    __syncthreads();
    s[threadIdx.x] += t;
    __syncthreads();
  }
  if (i < NN) rowptr[i] = s[threadIdx.x] - v;  // exclusive (local)
  if (threadIdx.x == 255) bsums[blockIdx.x] = s[255];
}

__global__ __launch_bounds__(256) void k_scan2(int* __restrict__ bsums,
                                               int* __restrict__ rowptr, int nb) {
  __shared__ int s[256];
  int v = (threadIdx.x < nb) ? bsums[threadIdx.x] : 0;
  s[threadIdx.x] = v;
  __syncthreads();
  for (int off = 1; off < 256; off <<= 1) {
    int t = (threadIdx.x >= off) ? s[threadIdx.x - off] : 0;
    __syncthreads();
    s[threadIdx.x] += t;
    __syncthreads();
  }
  if (threadIdx.x < nb) bsums[threadIdx.x] = s[threadIdx.x] - v;  // exclusive
  if (threadIdx.x == 0) rowptr[NN] = NE;
}

__global__ __launch_bounds__(256) void k_scan3(const int* __restrict__ hist,
                                               int* __restrict__ rowptr,
                                               const int* __restrict__ bsums,
                                               float* __restrict__ dinv) {
  int i = blockIdx.x * 256 + threadIdx.x;
  if (i < NN) {
    rowptr[i] += bsums[blockIdx.x];
    dinv[i] = rsqrtf((float)(hist[i] + 1));  // +1 self-loop; deg >= 1 always
  }
}

__global__ __launch_bounds__(256) void k_fill(const int* __restrict__ src,
                                              const int* __restrict__ dst,
                                              const int* __restrict__ rowptr,
                                              int* __restrict__ fill,
                                              int* __restrict__ csr) {
  int e = blockIdx.x * 256 + threadIdx.x;
  if (e < NE) {
    int d = dst[e];
    int p = rowptr[d] + atomicAdd(&fill[d], 1);
    csr[p] = src[e];
  }
}

// ---------------- prep: W (fp32 [k][n]) -> Wt (bf16 [n][k]) ----------------
__global__ __launch_bounds__(256) void k_prep_w(const float* __restrict__ W,
                                                uint16_t* __restrict__ Wt) {
  __shared__ float t[32][33];
  int bx = blockIdx.x & 7, by = blockIdx.x >> 3;
  int tx = threadIdx.x & 31, ty = threadIdx.x >> 5;  // 32 x 8
#pragma unroll
  for (int p = 0; p < 4; ++p)
    t[ty + p * 8][tx] = W[(size_t)(by * 32 + ty + p * 8) * 256 + bx * 32 + tx];
  __syncthreads();
#pragma unroll
  for (int p = 0; p < 4; ++p)
    Wt[(size_t)(bx * 32 + ty + p * 8) * 256 + by * 32 + tx] = f2bf(t[tx][ty + p * 8]);
}

// ---------------- prep: x fp32 -> hi/lo bf16 (exact split) ----------------
__global__ __launch_bounds__(256) void k_split(const float* __restrict__ x,
                                               uint16_t* __restrict__ hi,
                                               uint16_t* __restrict__ lo) {
  size_t i = (size_t)(blockIdx.x * 256 + threadIdx.x) * 4;  // 12.8M floats total
  float4 v = *(const float4*)(x + i);
  float a[4] = {v.x, v.y, v.z, v.w};
  ushort4v h, l;
#pragma unroll
  for (int u = 0; u < 4; ++u) {
    uint16_t hh = f2bf(a[u]);
    h[u] = hh;
    l[u] = f2bf(a[u] - bf2f(hh));
  }
  *(ushort4v*)(hi + i) = h;
  *(ushort4v*)(lo + i) = l;
}

// ---------------- GEMM (m97-style): out slice-major, prescaled by dinv[row] ----------
// SPLIT: A = Ah+Al (hi/lo bf16, row-major NPAD x 256).
// ASL:   A is slice-major bf16 [8][NPAD][32] (k-slice = k0/32).
// Wt: bf16 [256 n][256 k]. Output g2: [8][NN][32] bf16, g2_row = dinv[row]*(A@W)[row].
#define BM 128
#define BN 128
#define BK 32

template <int SPLIT, int ASL>
__global__ __launch_bounds__(256) void k_gemm(const uint16_t* __restrict__ Ah,
                                              const uint16_t* __restrict__ Al,
                                              const uint16_t* __restrict__ Wt,
                                              const float* __restrict__ dinv,
                                              uint16_t* __restrict__ g2, int M) {
  __shared__ short Ash[BM * BK];
  __shared__ short Asl[BM * BK];
  __shared__ short Bs[BN * BK];

  const int tid = threadIdx.x;
  const int wave = tid >> 6, lane = tid & 63;
  const int wm = wave >> 1, wn = wave & 1;
  const int m16 = lane & 15, q = lane >> 4;
  const int rowBase = blockIdx.x * BM;
  const int colBase = blockIdx.y * BN;
  const int rsub = lane >> 2;          // 0..15
  const int kch = (lane & 3) * 8;      // bf16-elem offset within BK chunk

  floatx4 acc[4][4];
#pragma unroll
  for (int i = 0; i < 4; ++i)
#pragma unroll
    for (int j = 0; j < 4; ++j) acc[i][j] = (floatx4)(0.0f);

  for (int k0 = 0; k0 < DIM; k0 += BK) {
    __syncthreads();
#pragma unroll
    for (int p = 0; p < 2; ++p) {
      int rb = wave * 16 + p * 64;
      if (ASL) {
        const uint16_t* As0 = Ah + (size_t)(k0 >> 5) * NPAD * 32;
        stage16(As0 + (size_t)(rowBase + rb + rsub) * 32 + kch, &Ash[rb * BK], lane);
      } else {
        stage16(Ah + (size_t)(rowBase + rb + rsub) * DIM + k0 + kch, &Ash[rb * BK], lane);
        if (SPLIT)
          stage16(Al + (size_t)(rowBase + rb + rsub) * DIM + k0 + kch, &Asl[rb * BK], lane);
      }
      stage16(Wt + (size_t)(colBase + rb + rsub) * DIM + k0 + kch, &Bs[rb * BK], lane);
    }
    __syncthreads();

    short8 ah[4], al[4], b[4];
#pragma unroll
    for (int i = 0; i < 4; ++i) {
      int r = wm * 64 + i * 16 + m16;
      ah[i] = *(const short8*)(&Ash[r * BK + q * 8]);
      if (SPLIT) al[i] = *(const short8*)(&Asl[r * BK + q * 8]);
    }
#pragma unroll
    for (int j = 0; j < 4; ++j) {
      int n = wn * 64 + j * 16 + m16;
      b[j] = *(const short8*)(&Bs[n * BK + q * 8]);
    }
#pragma unroll
    for (int i = 0; i < 4; ++i)
#pragma unroll
      for (int j = 0; j < 4; ++j) {
        if (SPLIT)
          acc[i][j] = __builtin_amdgcn_mfma_f32_16x16x32_bf16(al[i], b[j], acc[i][j], 0, 0, 0);
        acc[i][j] = __builtin_amdgcn_mfma_f32_16x16x32_bf16(ah[i], b[j], acc[i][j], 0, 0, 0);
      }
  }

  // epilogue: C/D layout col = lane&15, row = q*4 + reg; prescale by dinv[row],
  // write slice-major [8][NN][32].
#pragma unroll
  for (int i = 0; i < 4; ++i) {
#pragma unroll
    for (int reg = 0; reg < 4; ++reg) {
      int row = rowBase + wm * 64 + i * 16 + q * 4 + reg;
      if (row < M) {
        float dd = dinv[row];
#pragma unroll
        for (int j = 0; j < 4; ++j) {
          int col = colBase + wn * 64 + j * 16 + m16;
          int sl = col >> 5, cc = col & 31;
          g2[(size_t)sl * NN * 32 + (size_t)row * 32 + cc] = f2bf(acc[i][j][reg] * dd);
        }
      }
    }
  }
}

// ---------------- Aggregation: XCD-sliced pull, throughput structure ----------------
// slice = blockIdx&7 (XCD-affine); 1024 blocks/slice -> 4096 waves/slice, max occupancy.
// Wave = 4 quarter-waves x 16 lanes; each qw handles one edge (64B row, ushort2/lane),
// 2 gathers in flight (unroll e, e+4); features stay in-lane; 2 shfl steps per dst.
// g2 rows prescaled by dinv[src]: out[d] = post(dinv[d]*sum(rows) + b).
// FINAL=0: h1 slice-major bf16 [8][NPAD][32].  FINAL=1: out=(x+relu)*0.5 row-major fp32.
template <int FINAL>
__global__ __launch_bounds__(256) void k_agg(const uint16_t* __restrict__ g2,
                                             const int* __restrict__ rowptr,
                                             const int* __restrict__ csr,
                                             const float* __restrict__ dinv,
                                             const float* __restrict__ bias,
                                             const float* __restrict__ x,
                                             uint16_t* __restrict__ outb,
                                             float* __restrict__ outf) {
  const int slice = blockIdx.x & 7;
  const int nb = blockIdx.x >> 3;                 // 0..1023
  const int wave = threadIdx.x >> 6, lane = threadIdx.x & 63;
  const int qw = lane >> 4, li = lane & 15;       // 4 edge-groups x 16 lanes
  const uint16_t* gs = g2 + (size_t)slice * NN * 32;
  const int fo = li * 2;                          // 2 feats per lane
  const int w4 = nb * 4 + wave;                   // wave id within slice: 0..4095

  for (int d = w4; d < NN; d += 4096) {
    int e0 = rowptr[d], e1 = rowptr[d + 1];
    float a0, a1;
    if (qw == 0) {  // self row (prescaled by dinv[d] already)
      ushort2v sv = *(const ushort2v*)(gs + (size_t)d * 32 + fo);
      a0 = bf2f(sv[0]); a1 = bf2f(sv[1]);
    } else {
      a0 = 0.f; a1 = 0.f;
    }
    int e = e0 + qw;
    for (; e + 4 < e1; e += 8) {  // 2 independent gathers in flight
      int s0 = csr[e], s1 = csr[e + 4];
      ushort2v v0 = *(const ushort2v*)(gs + (size_t)s0 * 32 + fo);
      ushort2v v1 = *(const ushort2v*)(gs + (size_t)s1 * 32 + fo);
      a0 += bf2f(v0[0]) + bf2f(v1[0]);
      a1 += bf2f(v0[1]) + bf2f(v1[1]);
    }
    if (e < e1) {
      int s = csr[e];
      ushort2v v = *(const ushort2v*)(gs + (size_t)s * 32 + fo);
      a0 += bf2f(v[0]);
      a1 += bf2f(v[1]);
    }
    // combine 4 quarter-waves -> lanes 0..15
    a0 += __shfl_down(a0, 16); a1 += __shfl_down(a1, 16);
    a0 += __shfl_down(a0, 32); a1 += __shfl_down(a1, 32);

    if (qw == 0) {
      float dd = dinv[d];
      float2 bv = *(const float2*)(bias + slice * 32 + fo);
      float r0 = fmaxf(dd * a0 + bv.x, 0.f);
      float r1 = fmaxf(dd * a1 + bv.y, 0.f);
      if (FINAL) {
        float2 xv = *(const float2*)(x + (size_t)d * DIM + slice * 32 + fo);
        float2 o;
        o.x = (xv.x + r0) * 0.5f;
        o.y = (xv.y + r1) * 0.5f;
        *(float2*)(outf + (size_t)d * DIM + slice * 32 + fo) = o;
      } else {
        ushort2v o;
        o[0] = f2bf(r0); o[1] = f2bf(r1);
        *(ushort2v*)(outb + ((size_t)slice * NPAD + d) * 32 + fo) = o;
      }
    }
  }
}

// ---------------- launch ----------------
extern "C" void kernel_launch(void* const* d_in, const int* in_sizes, int n_in,
                              void* d_out, int out_size, void* d_ws, size_t ws_size,
                              hipStream_t stream) {
  const float* x  = (const float*)d_in[0];
  const int*   ei = (const int*)d_in[1];   // [2 x NE]: src row, then dst row
  const float* W1 = (const float*)d_in[2];
  const float* b1 = (const float*)d_in[3];
  const float* W2 = (const float*)d_in[4];
  const float* b2 = (const float*)d_in[5];
  float* out = (float*)d_out;

  // workspace layout (all bf16 arrays 16B-aligned)
  int*      hist   = (int*)d_ws;               // NN
  int*      fill   = hist + NN;                // NN
  int*      rowptr = fill + NN;                // NN+1 (padded to 50008)
  int*      bsums  = rowptr + 50008;           // 256
  int*      csr    = bsums + 256;              // NE
  float*    dinv   = (float*)(csr + NE);       // NN
  uint16_t* Wt1    = (uint16_t*)(dinv + NN);   // 256*256
  uint16_t* Wt2    = Wt1 + 256 * 256;          // 256*256
  uint16_t* x_hi   = Wt2 + 256 * 256;          // NPAD*DIM row-major
  uint16_t* x_lo   = x_hi + (size_t)NPAD * DIM;
  uint16_t* g2     = x_lo + (size_t)NPAD * DIM;  // [8][NN][32] slice-major
  uint16_t* h1     = g2 + (size_t)NN * DIM;      // [8][NPAD][32] slice-major

  const int* esrc = ei;
  const int* edst = ei + NE;

  k_zero<<<(2 * NN + 255) / 256, 256, 0, stream>>>(hist, 2 * NN);
  k_hist<<<(NE + 255) / 256, 256, 0, stream>>>(edst, hist);
  k_scan1<<<196, 256, 0, stream>>>(hist, rowptr, bsums);
  k_scan2<<<1, 256, 0, stream>>>(bsums, rowptr, 196);
  k_scan3<<<196, 256, 0, stream>>>(hist, rowptr, bsums, dinv);
  k_fill<<<(NE + 255) / 256, 256, 0, stream>>>(esrc, edst, rowptr, fill, csr);

  k_prep_w<<<64, 256, 0, stream>>>(W1, Wt1);
  k_prep_w<<<64, 256, 0, stream>>>(W2, Wt2);
  k_split<<<12500, 256, 0, stream>>>(x, x_hi, x_lo);  // 12.8M floats / 4 / 256

  dim3 ggrid((NN + BM - 1) / BM, DIM / BN);
  k_gemm<1, 0><<<ggrid, 256, 0, stream>>>(x_hi, x_lo, Wt1, dinv, g2, NN);
  k_agg<0><<<8192, 256, 0, stream>>>(g2, rowptr, csr, dinv, b1, nullptr, h1, nullptr);
  k_gemm<0, 1><<<ggrid, 256, 0, stream>>>(h1, nullptr, Wt2, dinv, g2, NN);
  k_agg<1><<<8192, 256, 0, stream>>>(g2, rowptr, csr, dinv, b2, x, nullptr, out);
}